// Round 1
// baseline (203.480 us; speedup 1.0000x reference)
//
#include <hip/hip_runtime.h>

// Problem geometry (derived at launch, these are the expected values):
//   L = 16384 tokens, Lc = 8192 chunks, H = 4096 hidden
// Exact two-pass segmented linear-recurrence scan:
//   y_i = A_i * y_{i-1} + Pc_i * concept_i   (A_i scalar per chunk, shared over H)
// Pass A: per-segment summaries (B_end[H], A_seg scalar)
// Pass B: chain carries across segments (per-channel independent)
// Pass C: rescan each segment from exact carry, write output token rows fused.

#define SEG 64      // chunks per segment
#define TPB 256     // threads per block (streaming passes)
#define SETUP_T 1024

// ---------------- setup: decode mask, build start[], A[], Pc[] ----------------
__global__ void setup_kernel(const unsigned char* __restrict__ mask,
                             const float* __restrict__ probs,
                             float* __restrict__ A, float* __restrict__ Pc,
                             int* __restrict__ start, int L, int Lc) {
    __shared__ int flag;
    __shared__ int cnt[SETUP_T];
    const int t = threadIdx.x;
    if (t == 0) flag = 0;
    __syncthreads();

    // Detect encoding: if mask is int32 (values 0/1), every byte at p%4!=0 is 0.
    // A u8 bool mask with any True at a non-multiple-of-4 position sets flag.
    int local = 0;
    for (int p = t; p < L; p += SETUP_T) {
        if ((p & 3) && mask[p]) local = 1;
    }
    if (local) atomicOr(&flag, 1);
    __syncthreads();
    const bool isU8 = (flag != 0);
    const int* mask_i32 = (const int*)mask;

    // per-thread counts over a contiguous token range
    const int per = (L + SETUP_T - 1) / SETUP_T;   // 16
    const int t0 = t * per;
    int c = 0;
    for (int k = 0; k < per; ++k) {
        int tok = t0 + k;
        if (tok < L) {
            int m = isU8 ? (mask[tok] != 0) : (mask_i32[tok] != 0);
            c += m;
        }
    }
    cnt[t] = c;
    __syncthreads();
    // Hillis-Steele inclusive scan over 1024 counts
    for (int off = 1; off < SETUP_T; off <<= 1) {
        int v = 0;
        if (t >= off) v = cnt[t - off];
        __syncthreads();
        if (t >= off) cnt[t] += v;
        __syncthreads();
    }
    int rank = (t == 0) ? 0 : cnt[t - 1];
    for (int k = 0; k < per; ++k) {
        int tok = t0 + k;
        if (tok < L) {
            int m = isU8 ? (mask[tok] != 0) : (mask_i32[tok] != 0);
            if (m) {
                if (rank < Lc) {
                    start[rank] = tok;
                    float p = probs[tok];
                    A[rank]  = (rank == 0) ? 0.0f : (1.0f - p);
                    Pc[rank] = (rank == 0) ? 1.0f : p;
                }
                rank++;
            }
        }
    }
    if (t == 0) start[Lc] = L;
}

// ---------------- pass A: per-segment summaries ----------------
__global__ void __launch_bounds__(TPB)
segsum_kernel(const float* __restrict__ cpt,
              const float* __restrict__ A, const float* __restrict__ Pc,
              float* __restrict__ Bend, float* __restrict__ Aseg,
              int H, int CG) {
    const int g  = blockIdx.x / CG;
    const int cg = blockIdx.x % CG;
    const int ch = cg * (TPB * 4) + threadIdx.x * 4;

    __shared__ float sA[SEG], sP[SEG];
    const int i0 = g * SEG;
    for (int k = threadIdx.x; k < SEG; k += TPB) { sA[k] = A[i0 + k]; sP[k] = Pc[i0 + k]; }
    __syncthreads();

    float4 y = make_float4(0.f, 0.f, 0.f, 0.f);
    float pa = 1.0f;
    const float4* cp = (const float4*)(cpt + (size_t)i0 * H + ch);
    const int strideF4 = H / 4;
#pragma unroll 8
    for (int k = 0; k < SEG; ++k) {
        float a = sA[k], p = sP[k];
        float4 c = cp[(size_t)k * strideF4];
        y.x = a * y.x + p * c.x;
        y.y = a * y.y + p * c.y;
        y.z = a * y.z + p * c.z;
        y.w = a * y.w + p * c.w;
        pa *= a;
    }
    *(float4*)(Bend + (size_t)g * H + ch) = y;
    if (threadIdx.x == 0 && cg == 0) Aseg[g] = pa;
}

// ---------------- pass B: chain carries across segments ----------------
__global__ void __launch_bounds__(TPB)
carry_kernel(const float* __restrict__ Bend, const float* __restrict__ Aseg,
             float* __restrict__ carry, int H, int G) {
    const int ch = blockIdx.x * (TPB * 4) + threadIdx.x * 4;
    float4 cr = make_float4(0.f, 0.f, 0.f, 0.f);
    *(float4*)(carry + ch) = cr;               // segment 0 carry = 0
    for (int g = 1; g < G; ++g) {
        float a = Aseg[g - 1];
        float4 b = *(const float4*)(Bend + (size_t)(g - 1) * H + ch);
        cr.x = b.x + a * cr.x;
        cr.y = b.y + a * cr.y;
        cr.z = b.z + a * cr.z;
        cr.w = b.w + a * cr.w;
        *(float4*)(carry + (size_t)g * H + ch) = cr;
    }
}

// ---------------- pass C: rescan + fused plug-back write ----------------
__global__ void __launch_bounds__(TPB)
scan_write_kernel(const float* __restrict__ cpt,
                  const float* __restrict__ A, const float* __restrict__ Pc,
                  const int* __restrict__ start, const float* __restrict__ carry,
                  float* __restrict__ out, int H, int CG) {
    const int g  = blockIdx.x / CG;
    const int cg = blockIdx.x % CG;
    const int ch = cg * (TPB * 4) + threadIdx.x * 4;

    __shared__ float sA[SEG], sP[SEG];
    __shared__ int sS[SEG + 1];
    const int i0 = g * SEG;
    for (int k = threadIdx.x; k < SEG; k += TPB)    { sA[k] = A[i0 + k]; sP[k] = Pc[i0 + k]; }
    for (int k = threadIdx.x; k < SEG + 1; k += TPB){ sS[k] = start[i0 + k]; }
    __syncthreads();

    float4 y = *(const float4*)(carry + (size_t)g * H + ch);
    const int strideF4 = H / 4;
    const float4* cp = (const float4*)(cpt + (size_t)i0 * H + ch);
#pragma unroll 4
    for (int k = 0; k < SEG; ++k) {
        float a = sA[k], p = sP[k];
        float4 c = cp[(size_t)k * strideF4];
        y.x = a * y.x + p * c.x;
        y.y = a * y.y + p * c.y;
        y.z = a * y.z + p * c.z;
        y.w = a * y.w + p * c.w;
        int te = sS[k + 1];
        for (int t = sS[k]; t < te; ++t) {
            *(float4*)(out + (size_t)t * H + ch) = y;
        }
    }
}

extern "C" void kernel_launch(void* const* d_in, const int* in_sizes, int n_in,
                              void* d_out, int out_size, void* d_ws, size_t ws_size,
                              hipStream_t stream) {
    const float* cpt  = (const float*)d_in[0];          // [1, Lc, H] f32
    const float* probs = (const float*)d_in[1];         // [1, L, 1] f32
    const unsigned char* mask = (const unsigned char*)d_in[2]; // [1, L] bool/int

    const int L  = in_sizes[1];            // 16384
    const int H  = out_size / L;           // 4096
    const int Lc = in_sizes[0] / H;        // 8192
    const int G  = Lc / SEG;               // 128
    const int CG = H / (TPB * 4);          // 4 channel groups of 1024

    // workspace bump allocator (16B aligned)
    char* ws = (char*)d_ws;
    size_t off = 0;
    auto alloc = [&](size_t bytes) {
        size_t o = off;
        off += (bytes + 15) & ~(size_t)15;
        return (void*)(ws + o);
    };
    float* A     = (float*)alloc((size_t)Lc * 4);
    float* Pc    = (float*)alloc((size_t)Lc * 4);
    int*   start = (int*)  alloc((size_t)(Lc + 1) * 4);
    float* Aseg  = (float*)alloc((size_t)G * 4);
    float* Bend  = (float*)alloc((size_t)G * H * 4);
    float* carry = (float*)alloc((size_t)G * H * 4);
    (void)ws_size;

    hipLaunchKernelGGL(setup_kernel, dim3(1), dim3(SETUP_T), 0, stream,
                       mask, probs, A, Pc, start, L, Lc);
    hipLaunchKernelGGL(segsum_kernel, dim3(G * CG), dim3(TPB), 0, stream,
                       cpt, A, Pc, Bend, Aseg, H, CG);
    hipLaunchKernelGGL(carry_kernel, dim3(H / (TPB * 4)), dim3(TPB), 0, stream,
                       Bend, Aseg, carry, H, G);
    hipLaunchKernelGGL(scan_write_kernel, dim3(G * CG), dim3(TPB), 0, stream,
                       cpt, A, Pc, start, carry, out_size ? (float*)d_out : nullptr, H, CG);
}